// Round 15
// baseline (159.997 us; speedup 1.0000x reference)
//
#include <hip/hip_runtime.h>

// UV_Aggregator, gather-split (spill-fixed rerun of the R2 idea):
//  mlp_kernel: flat 204800 rows, 64/wave -> 3200 blocks ALL gathering at t=0
//              (max HBM concurrency on the L3-cold v2e gather), layer1+2,
//              O (f16) -> workspace, strict-phase LDS, (64,2).
//  att2_kernel: 2 b's per wave (R14 ILP win), O fragments straight from ws,
//              hoisted uv_rep, register-held OA, (64,2).

#define LNB 50

typedef _Float16 f16x8 __attribute__((ext_vector_type(8)));
typedef float    f32x4 __attribute__((ext_vector_type(4)));

// byte offset into a [64][64] f16 tile (128 B rows), XOR swizzle (T2-style)
__device__ __forceinline__ int swz(int r, int bytecol) {
  return (r * 128 + bytecol) ^ ((r & 7) << 4);
}

// load 8 consecutive fp32, round-to-nearest-even to f16
__device__ __forceinline__ f16x8 cvt8(const float* __restrict__ p) {
  const float4 lo = *(const float4*)p;
  const float4 hi = *(const float4*)(p + 4);
  f16x8 a;
  a[0] = (_Float16)lo.x; a[1] = (_Float16)lo.y;
  a[2] = (_Float16)lo.z; a[3] = (_Float16)lo.w;
  a[4] = (_Float16)hi.x; a[5] = (_Float16)hi.y;
  a[6] = (_Float16)hi.z; a[7] = (_Float16)hi.w;
  return a;
}

// fp32 weights -> f16 in workspace (re-run every call; ws re-poisoned each time)
__global__ void prep_weights(const float* __restrict__ w1, const float* __restrict__ w2,
                             const float* __restrict__ a1, const float* __restrict__ a2,
                             _Float16* __restrict__ wf) {
  int i = blockIdx.x * 256 + threadIdx.x;
  if (i < 8192) wf[i]         = (_Float16)w1[i];   // w_r1_w (64x128)
  if (i < 4096) wf[8192 + i]  = (_Float16)w2[i];   // w_r2_w (64x64)
  if (i < 8192) wf[12288 + i] = (_Float16)a1[i];   // att1_w (64x128)
  if (i < 4096) wf[20480 + i] = (_Float16)a2[i];   // att2_w (64x64)
}

// ---------------- Kernel A: flat-row MLP ------------------------------------
// grid 3200 x 64 (one wave per 64 flat rows; 204800 rows exactly)
__global__ __launch_bounds__(64, 2) void mlp_kernel(
    const int* __restrict__ hist_uv,
    const int* __restrict__ hist_r,
    const float* __restrict__ v2e,
    const float* __restrict__ r2e,
    const float* __restrict__ b1,
    const float* __restrict__ b2,
    const _Float16* __restrict__ wf,
    _Float16* __restrict__ ows) {
  __shared__ _Float16 T[64 * 64];   // 8 KB
  const int lane = threadIdx.x;
  const int lr = lane & 15;
  const int kq = lane >> 4;
  const int r0 = blockIdx.x * 64;

  const _Float16* w1f = wf;
  const _Float16* w2f = wf + 8192;

  // ---- Phase 1: H = relu([e_uv;e_r] @ W1^T + b1)  [T: WRITE] -------------
  {
    f16x8 Bf[4][4];
#pragma unroll
    for (int kt = 0; kt < 4; ++kt)
#pragma unroll
      for (int nt = 0; nt < 4; ++nt)
        Bf[kt][nt] = *(const f16x8*)(w1f + (nt * 16 + lr) * 128 + kt * 32 + kq * 8);

    float bias1[4];
#pragma unroll
    for (int nt = 0; nt < 4; ++nt) bias1[nt] = b1[nt * 16 + lr];

#pragma unroll
    for (int m = 0; m < 4; ++m) {
      const int r = r0 + m * 16 + lr;
      const int iu = hist_uv[r];
      const int ir = hist_r[r];
      const float* pu = v2e + (size_t)iu * 64;
      const float* pr = r2e + (size_t)ir * 64;   // R=5 -> cache-resident
      f16x8 A[4];
      A[0] = cvt8(pu + kq * 8);
      A[1] = cvt8(pu + 32 + kq * 8);
      A[2] = cvt8(pr + kq * 8);
      A[3] = cvt8(pr + 32 + kq * 8);
#pragma unroll
      for (int nt = 0; nt < 4; ++nt) {
        f32x4 acc = {0.f, 0.f, 0.f, 0.f};
#pragma unroll
        for (int kt = 0; kt < 4; ++kt)
          acc = __builtin_amdgcn_mfma_f32_16x16x32_f16(A[kt], Bf[kt][nt], acc, 0, 0, 0);
        const int c = nt * 16 + lr;
#pragma unroll
        for (int j = 0; j < 4; ++j) {
          const int row = m * 16 + kq * 4 + j;
          const float v = fmaxf(acc[j] + bias1[nt], 0.f);
          *(_Float16*)((char*)T + swz(row, 2 * c)) = (_Float16)v;
        }
      }
    }
  }
  __syncthreads();

  // ---- Phase 2: H A-fragments -> registers  [T: READ] --------------------
  f16x8 HA0[4], HA1[4];
#pragma unroll
  for (int m = 0; m < 4; ++m) {
    const int r = m * 16 + lr;
    HA0[m] = *(const f16x8*)((char*)T + swz(r, 2 * (kq * 8)));
    HA1[m] = *(const f16x8*)((char*)T + swz(r, 2 * (32 + kq * 8)));
  }
  __syncthreads();

  // ---- Phase 3: O = relu(H @ W2^T + b2) from regs  [T: WRITE] ------------
  {
    f16x8 Bf[2][4];
#pragma unroll
    for (int kt = 0; kt < 2; ++kt)
#pragma unroll
      for (int nt = 0; nt < 4; ++nt)
        Bf[kt][nt] = *(const f16x8*)(w2f + (nt * 16 + lr) * 64 + kt * 32 + kq * 8);

    float bias2[4];
#pragma unroll
    for (int nt = 0; nt < 4; ++nt) bias2[nt] = b2[nt * 16 + lr];

#pragma unroll
    for (int m = 0; m < 4; ++m) {
#pragma unroll
      for (int nt = 0; nt < 4; ++nt) {
        f32x4 acc = {0.f, 0.f, 0.f, 0.f};
        acc = __builtin_amdgcn_mfma_f32_16x16x32_f16(HA0[m], Bf[0][nt], acc, 0, 0, 0);
        acc = __builtin_amdgcn_mfma_f32_16x16x32_f16(HA1[m], Bf[1][nt], acc, 0, 0, 0);
        const int c = nt * 16 + lr;
#pragma unroll
        for (int j = 0; j < 4; ++j) {
          const int row = m * 16 + kq * 4 + j;
          const float v = fmaxf(acc[j] + bias2[nt], 0.f);
          *(_Float16*)((char*)T + swz(row, 2 * c)) = (_Float16)v;
        }
      }
    }
  }
  __syncthreads();

  // ---- Phase 4: coalesced O writeback (ds_read_b128 + store_dwordx4) -----
  {
    char* dst = (char*)ows + (size_t)r0 * 128;
#pragma unroll
    for (int p = 0; p < 8; ++p) {
      const int idx = p * 1024 + lane * 16;
      f16x8 v = *(const f16x8*)((const char*)T + swz(idx >> 7, idx & 127));
      *(f16x8*)(dst + idx) = v;
    }
  }
}

// ---------------- Kernel B: attention, 2 b's per wave -----------------------
// grid 2048 x 64
__global__ __launch_bounds__(64, 2) void att2_kernel(
    const int* __restrict__ nodes,
    const float* __restrict__ u2e,
    const float* __restrict__ ab1,
    const float* __restrict__ ab2,
    const float* __restrict__ a3w,
    const _Float16* __restrict__ wf,
    const _Float16* __restrict__ ows,
    float* __restrict__ out) {
  __shared__ _Float16 T[2][64 * 64];   // P tiles
  __shared__ float scb[2][64];
  __shared__ float wtb[2][64];
  const int lane = threadIdx.x;
  const int lr = lane & 15;
  const int kq = lane >> 4;
  const int b0 = blockIdx.x * 2;

  const _Float16* a1f = wf + 12288;
  const _Float16* a2f = wf + 20480;

  // ---- Phase A: O A-fragments from workspace (f16, direct) ---------------
  f16x8 OA0[2][4], OA1[2][4];
#pragma unroll
  for (int q = 0; q < 2; ++q) {
    const _Float16* ob = ows + (size_t)(b0 + q) * LNB * 64;
#pragma unroll
    for (int m = 0; m < 4; ++m) {
      const int r = m * 16 + lr;
      if (r < LNB) {
        OA0[q][m] = *(const f16x8*)(ob + (size_t)r * 64 + kq * 8);
        OA1[q][m] = *(const f16x8*)(ob + (size_t)r * 64 + 32 + kq * 8);
      } else {
#pragma unroll
        for (int i = 0; i < 8; ++i) { OA0[q][m][i] = (_Float16)0.f; OA1[q][m][i] = (_Float16)0.f; }
      }
    }
  }

  // ---- Phase B: P = relu([O ; uv_rep] @ A1^T + ab1)  [T: WRITE] ----------
  {
    // uv_rep contribution is row-constant per b: compute once per (q,nt)
    f32x4 acc_u[2][4];
    {
      f16x8 Bu[2][4];   // shared by both b-chains
#pragma unroll
      for (int kt = 0; kt < 2; ++kt)
#pragma unroll
        for (int nt = 0; nt < 4; ++nt)
          Bu[kt][nt] = *(const f16x8*)(a1f + (nt * 16 + lr) * 128 + (kt + 2) * 32 + kq * 8);
#pragma unroll
      for (int q = 0; q < 2; ++q) {
        const int node = nodes[b0 + q];
        const f16x8 U2 = cvt8(u2e + (size_t)node * 64 + kq * 8);
        const f16x8 U3 = cvt8(u2e + (size_t)node * 64 + 32 + kq * 8);
#pragma unroll
        for (int nt = 0; nt < 4; ++nt) {
          f32x4 acc = {0.f, 0.f, 0.f, 0.f};
          acc = __builtin_amdgcn_mfma_f32_16x16x32_f16(U2, Bu[0][nt], acc, 0, 0, 0);
          acc = __builtin_amdgcn_mfma_f32_16x16x32_f16(U3, Bu[1][nt], acc, 0, 0, 0);
          acc_u[q][nt] = acc;
        }
      }
    }

    f16x8 Bf[2][4];
#pragma unroll
    for (int kt = 0; kt < 2; ++kt)
#pragma unroll
      for (int nt = 0; nt < 4; ++nt)
        Bf[kt][nt] = *(const f16x8*)(a1f + (nt * 16 + lr) * 128 + kt * 32 + kq * 8);

    float biasa1[4];
#pragma unroll
    for (int nt = 0; nt < 4; ++nt) biasa1[nt] = ab1[nt * 16 + lr];

#pragma unroll
    for (int q = 0; q < 2; ++q) {
      char* Tq = (char*)T[q];
#pragma unroll
      for (int m = 0; m < 4; ++m) {
#pragma unroll
        for (int nt = 0; nt < 4; ++nt) {
          f32x4 acc = acc_u[q][nt];
          acc = __builtin_amdgcn_mfma_f32_16x16x32_f16(OA0[q][m], Bf[0][nt], acc, 0, 0, 0);
          acc = __builtin_amdgcn_mfma_f32_16x16x32_f16(OA1[q][m], Bf[1][nt], acc, 0, 0, 0);
          const int c = nt * 16 + lr;
#pragma unroll
          for (int j = 0; j < 4; ++j) {
            const int row = m * 16 + kq * 4 + j;
            const float v = fmaxf(acc[j] + biasa1[nt], 0.f);
            *(_Float16*)(Tq + swz(row, 2 * c)) = (_Float16)v;
          }
        }
      }
    }
  }
  __syncthreads();

  // ---- Phase C: s = relu(P @ A2^T + ab2) . a3  [T: READ only] ------------
  {
    f16x8 Bf[2][4];
#pragma unroll
    for (int kt = 0; kt < 2; ++kt)
#pragma unroll
      for (int nt = 0; nt < 4; ++nt)
        Bf[kt][nt] = *(const f16x8*)(a2f + (nt * 16 + lr) * 64 + kt * 32 + kq * 8);

    float biasa2[4], a3c[4];
#pragma unroll
    for (int nt = 0; nt < 4; ++nt) {
      biasa2[nt] = ab2[nt * 16 + lr];
      a3c[nt] = a3w[nt * 16 + lr];
    }

#pragma unroll
    for (int m = 0; m < 4; ++m) {
      const int r = m * 16 + lr;
      f16x8 A0q[2], A1q[2];
#pragma unroll
      for (int q = 0; q < 2; ++q) {
        const char* Tq = (const char*)T[q];
        A0q[q] = *(const f16x8*)(Tq + swz(r, 2 * (kq * 8)));
        A1q[q] = *(const f16x8*)(Tq + swz(r, 2 * (32 + kq * 8)));
      }
      float part[2][4] = {{0.f,0.f,0.f,0.f},{0.f,0.f,0.f,0.f}};
#pragma unroll
      for (int nt = 0; nt < 4; ++nt) {
#pragma unroll
        for (int q = 0; q < 2; ++q) {
          f32x4 acc = {0.f, 0.f, 0.f, 0.f};
          acc = __builtin_amdgcn_mfma_f32_16x16x32_f16(A0q[q], Bf[0][nt], acc, 0, 0, 0);
          acc = __builtin_amdgcn_mfma_f32_16x16x32_f16(A1q[q], Bf[1][nt], acc, 0, 0, 0);
#pragma unroll
          for (int j = 0; j < 4; ++j) {
            const float v = fmaxf(acc[j] + biasa2[nt], 0.f);
            part[q][j] += v * a3c[nt];
          }
        }
      }
#pragma unroll
      for (int mask = 1; mask < 16; mask <<= 1)
#pragma unroll
        for (int q = 0; q < 2; ++q)
#pragma unroll
          for (int j = 0; j < 4; ++j) part[q][j] += __shfl_xor(part[q][j], mask);
      if (lr == 0) {
#pragma unroll
        for (int q = 0; q < 2; ++q)
#pragma unroll
          for (int j = 0; j < 4; ++j) scb[q][m * 16 + kq * 4 + j] = part[q][j];
      }
    }
  }
  __syncthreads();

  // ---- Phase D: softmax over neighbors (att3_b shift-invariant) ----------
  {
    float sv[2], mx[2], e[2], s[2];
#pragma unroll
    for (int q = 0; q < 2; ++q) { sv[q] = (lane < LNB) ? scb[q][lane] : -1e30f; mx[q] = sv[q]; }
#pragma unroll
    for (int mask = 1; mask < 64; mask <<= 1)
#pragma unroll
      for (int q = 0; q < 2; ++q) mx[q] = fmaxf(mx[q], __shfl_xor(mx[q], mask));
#pragma unroll
    for (int q = 0; q < 2; ++q) { e[q] = __expf(sv[q] - mx[q]); s[q] = e[q]; }
#pragma unroll
    for (int mask = 1; mask < 64; mask <<= 1)
#pragma unroll
      for (int q = 0; q < 2; ++q) s[q] += __shfl_xor(s[q], mask);
#pragma unroll
    for (int q = 0; q < 2; ++q) wtb[q][lane] = (lane < LNB) ? (e[q] / s[q]) : 0.f;
  }
  __syncthreads();

  // ---- Phase E: weighted sums from O register fragments ------------------
  {
    float wrow[2][4];
#pragma unroll
    for (int q = 0; q < 2; ++q)
#pragma unroll
      for (int m = 0; m < 4; ++m) wrow[q][m] = wtb[q][m * 16 + lr];

    float p0[2][8] = {{0,0,0,0,0,0,0,0},{0,0,0,0,0,0,0,0}};
    float p1[2][8] = {{0,0,0,0,0,0,0,0},{0,0,0,0,0,0,0,0}};
#pragma unroll
    for (int q = 0; q < 2; ++q)
#pragma unroll
      for (int m = 0; m < 4; ++m)
#pragma unroll
        for (int i = 0; i < 8; ++i) {
          p0[q][i] += wrow[q][m] * (float)OA0[q][m][i];
          p1[q][i] += wrow[q][m] * (float)OA1[q][m][i];
        }
#pragma unroll
    for (int mask = 1; mask < 16; mask <<= 1)
#pragma unroll
      for (int q = 0; q < 2; ++q)
#pragma unroll
        for (int i = 0; i < 8; ++i) {
          p0[q][i] += __shfl_xor(p0[q][i], mask);
          p1[q][i] += __shfl_xor(p1[q][i], mask);
        }
    if (lr == 0) {
#pragma unroll
      for (int q = 0; q < 2; ++q)
#pragma unroll
        for (int i = 0; i < 8; ++i) {
          scb[q][kq * 8 + i] = p0[q][i];
          scb[q][32 + kq * 8 + i] = p1[q][i];
        }
    }
  }
  __syncthreads();
#pragma unroll
  for (int q = 0; q < 2; ++q)
    out[(size_t)(b0 + q) * 64 + lane] = scb[q][lane];
}

extern "C" void kernel_launch(void* const* d_in, const int* in_sizes, int n_in,
                              void* d_out, int out_size, void* d_ws, size_t ws_size,
                              hipStream_t stream) {
  (void)in_sizes; (void)n_in; (void)out_size; (void)ws_size;
  const int* nodes = (const int*)d_in[0];
  const int* huv   = (const int*)d_in[1];
  const int* hr    = (const int*)d_in[2];
  // d_in[3] history_uvt: unused by reference
  const float* v2e = (const float*)d_in[4];
  const float* u2e = (const float*)d_in[5];
  const float* r2e = (const float*)d_in[6];
  const float* w1  = (const float*)d_in[7];
  const float* b1  = (const float*)d_in[8];
  const float* w2  = (const float*)d_in[9];
  const float* b2  = (const float*)d_in[10];
  const float* a1  = (const float*)d_in[11];
  const float* ab1 = (const float*)d_in[12];
  const float* a2  = (const float*)d_in[13];
  const float* ab2 = (const float*)d_in[14];
  const float* a3  = (const float*)d_in[15];
  // d_in[16] att3_b: constant shift inside softmax -> no effect on output

  _Float16* wf  = (_Float16*)d_ws;                   // 48 KB f16 weights
  _Float16* ows = (_Float16*)((char*)d_ws + 65536);  // O: 204800 x 64 f16 = 26.2 MB

  prep_weights<<<32, 256, 0, stream>>>(w1, w2, a1, a2, wf);
  mlp_kernel<<<3200, 64, 0, stream>>>(huv, hr, v2e, r2e, b1, b2, wf, ows);
  att2_kernel<<<2048, 64, 0, stream>>>(nodes, u2e, ab1, ab2, a3, wf, ows,
                                       (float*)d_out);
}